// Round 1
// 549.758 us; speedup vs baseline: 1.0859x; 1.0859x over previous
//
#include <hip/hip_runtime.h>
#include <hip/hip_bf16.h>

// ScaledDotProductAttention: B=8,H=16,S=512,D=512, fp32 in/out.
// out[b,h,s,d] = sum_t softmax_t(Q.K^T/sqrt(D))[s,t] * V[b,h,d,t]   (scores @ V^T)
//
// One workgroup (512 thr = 8 waves) = 64 Q rows of one head.
// Full 64x512 logit strip in registers (wave = 16 rows x 256 cols = 16 frags).
// v2: software-pipelined staging (issue-early/write-late, double-buffered smB,
//     ONE barrier per K-step), XOR-swizzled smB (kills 8-way write conflicts).

typedef __attribute__((ext_vector_type(4))) float floatx4;
typedef __attribute__((ext_vector_type(8))) short shortx8;

#define SEQ 512
#define DIM 512
#define MQ   64          // Q rows per workgroup
#define NTH 512          // threads per block (8 waves)
#define KCH  32          // k-chunk depth (one 16x16x32 MFMA step)
#define LDA 520          // Qs/Ps row stride in bf16 elems (260 dw % 32 = 4 -> reads 2-way)
#define LDBS 32          // smB row stride in bf16 elems, UNPADDED + XOR swizzle

__device__ __forceinline__ unsigned short f2bf(float f) {
  union { __hip_bfloat16 b; unsigned short u; } cv;
  cv.b = __float2bfloat16(f);
  return cv.u;
}

__device__ __forceinline__ uint2 cvt4(float4 f) {
  union { __hip_bfloat162 b; unsigned int u; } lo, hi;
  lo.b = __float22bfloat162_rn(make_float2(f.x, f.y));
  hi.b = __float22bfloat162_rn(make_float2(f.z, f.w));
  uint2 r; r.x = lo.u; r.y = hi.u;
  return r;
}

__global__ __launch_bounds__(NTH, 1)
void sdpa_kernel(const float* __restrict__ q, const float* __restrict__ k,
                 const float* __restrict__ v, float* __restrict__ out) {
  __shared__ unsigned short smA[MQ * LDA];        // Q tile (bf16), later P tile
  __shared__ unsigned short smB[2][SEQ * LDBS];   // double-buffered K/V chunk staging
  __shared__ float red[MQ][4];                    // [0..1]=rowmax halves, [2..3]=rowsum

  const int tid  = threadIdx.x;
  const int lane = tid & 63;
  const int wid  = tid >> 6;       // 0..7
  const int strip = wid >> 1;      // 0..3 : 16-row strip
  const int half  = wid & 1;       // 0..1 : 256-col half
  const int l15  = lane & 15;
  const int quad = lane >> 4;      // 0..3

  // XCD-aware swizzle: all 8 q-tiles of a head land on the same XCD (id%8).
  const int id = blockIdx.x;
  const int cx = id & 7;
  const int g  = id >> 3;
  const int qtile = g & 7;
  const int head  = ((g >> 3) << 3) | cx;

  const size_t hb = (size_t)head * (SEQ * DIM);
  const float* qh = q + hb + (size_t)qtile * MQ * DIM;
  const float* kh = k + hb;
  const float* vh = v + hb;
  float*       oh = out + hb + (size_t)qtile * MQ * DIM;

  const float scale = 0.044194173824159216f;  // 1/sqrt(512), folded into Q

  // ---- per-thread staging geometry (constant across chunks) ----
  // flat = i*512+tid -> row = i*64 + (tid>>3), 8B-unit c4 = tid&7
  // physical unit = c4 ^ (row&6); row&6 == r0&6 since i*64 % 8 == 0.
  const int r0 = tid >> 3;                         // base row 0..63
  const int c4 = tid & 7;                          // logical 8B unit
  const int sldx = r0 * LDBS + ((c4 ^ (r0 & 6)) << 2);  // swizzled short offset

  float4 rv[8];

  // ---- issue K chunk 0 loads (hide under Q staging) ----
  #pragma unroll
  for (int i = 0; i < 8; ++i)
    rv[i] = *(const float4*)(kh + (size_t)(i * 64 + r0) * DIM + (c4 << 2));

  // ---- Phase 0: load Q tile (64x512 fp32), scale, convert, -> smA ----
  {
    const int qc  = tid & 127;       // float4 index within row (const per thread)
    const int qr0 = tid >> 7;        // 0..3
    #pragma unroll
    for (int i = 0; i < 16; ++i) {
      int row = i * 4 + qr0;
      float4 f = *(const float4*)(qh + (size_t)row * DIM + (qc << 2));
      f.x *= scale; f.y *= scale; f.z *= scale; f.w *= scale;
      *(uint2*)(&smA[row * LDA + (qc << 2)]) = cvt4(f);
    }
  }

  // ---- write K0 into smB[0] ----
  #pragma unroll
  for (int i = 0; i < 8; ++i)
    *(uint2*)(&smB[0][i * 64 * LDBS + sldx]) = cvt4(rv[i]);
  __syncthreads();

  floatx4 acc[16];
  #pragma unroll
  for (int i = 0; i < 16; ++i) acc[i] = (floatx4)(0.0f);

  const int arow = (strip * 16 + l15) * LDA + quad * 8;        // + kc*KCH
  // b-frag read: brow&6 == l15&6 (ct*16 and half*256 are 0 mod 8)
  const int bu = (((quad << 1) ^ (l15 & 6)) << 2);             // swizzled short off

  // ---- Phase 1: logits = scaledQ . K^T  (pipelined: load kc+1 under MFMA kc)
  int cur = 0;
  for (int kc = 0; kc < 16; ++kc) {
    const float* src = (kc < 15) ? (kh + (kc + 1) * KCH) : vh;  // kc=15: prefetch V0
    #pragma unroll
    for (int i = 0; i < 8; ++i)
      rv[i] = *(const float4*)(src + (size_t)(i * 64 + r0) * DIM + (c4 << 2));

    shortx8 a = *(const shortx8*)(&smA[arow + kc * KCH]);
    #pragma unroll
    for (int ct = 0; ct < 16; ++ct) {
      int brow = half * 256 + ct * 16 + l15;
      shortx8 b = *(const shortx8*)(&smB[cur][brow * LDBS + bu]);
      acc[ct] = __builtin_amdgcn_mfma_f32_16x16x32_bf16(a, b, acc[ct], 0, 0, 0);
    }
    __builtin_amdgcn_sched_barrier(0);   // keep vmcnt-waits below the MFMAs
    #pragma unroll
    for (int i = 0; i < 8; ++i)
      *(uint2*)(&smB[cur ^ 1][i * 64 * LDBS + sldx]) = cvt4(rv[i]);
    __syncthreads();                     // ONE barrier per step
    cur ^= 1;
  }
  // cur == 0 here; smB[0] holds V chunk 0 (in flight / staged during kc=15).

  // ---- Phase 2: softmax over full 512-wide rows (fp32) ----
  // D-layout: value (ct,r) -> row strip*16 + quad*4 + r, col half*256 + ct*16 + l15
  float mx[4], sm[4];
  #pragma unroll
  for (int r = 0; r < 4; ++r) mx[r] = -1e30f;
  #pragma unroll
  for (int ct = 0; ct < 16; ++ct)
    #pragma unroll
    for (int r = 0; r < 4; ++r) mx[r] = fmaxf(mx[r], acc[ct][r]);
  #pragma unroll
  for (int off = 8; off >= 1; off >>= 1)
    #pragma unroll
    for (int r = 0; r < 4; ++r) mx[r] = fmaxf(mx[r], __shfl_xor(mx[r], off, 16));

  const int row0 = strip * 16 + quad * 4;
  if (l15 == 0) {
    #pragma unroll
    for (int r = 0; r < 4; ++r) red[row0 + r][half] = mx[r];
  }
  __syncthreads();
  #pragma unroll
  for (int r = 0; r < 4; ++r) {
    mx[r] = fmaxf(red[row0 + r][0], red[row0 + r][1]);
    sm[r] = 0.0f;
  }
  #pragma unroll
  for (int ct = 0; ct < 16; ++ct)
    #pragma unroll
    for (int r = 0; r < 4; ++r) {
      float e = __expf(acc[ct][r] - mx[r]);
      acc[ct][r] = e;
      sm[r] += e;
    }
  #pragma unroll
  for (int off = 8; off >= 1; off >>= 1)
    #pragma unroll
    for (int r = 0; r < 4; ++r) sm[r] += __shfl_xor(sm[r], off, 16);
  if (l15 == 0) {
    #pragma unroll
    for (int r = 0; r < 4; ++r) red[row0 + r][2 + half] = sm[r];
  }
  __syncthreads();
  float inv[4];
  #pragma unroll
  for (int r = 0; r < 4; ++r) inv[r] = 1.0f / (red[row0 + r][2] + red[row0 + r][3]);

  // write normalized P (bf16) into smA (Q is dead; all Q reads completed)
  #pragma unroll
  for (int ct = 0; ct < 16; ++ct) {
    int t = half * 256 + ct * 16 + l15;
    #pragma unroll
    for (int r = 0; r < 4; ++r) {
      smA[(row0 + r) * LDA + t] = f2bf(acc[ct][r] * inv[r]);
    }
  }
  __syncthreads();   // P visible to all waves before GEMM2 a-frag reads

  // ---- Phase 3: O = P . V^T (pipelined, V0 already staged) ----
  #pragma unroll
  for (int i = 0; i < 16; ++i) acc[i] = (floatx4)(0.0f);

  for (int tc = 0; tc < 16; ++tc) {
    if (tc < 15) {
      #pragma unroll
      for (int i = 0; i < 8; ++i)
        rv[i] = *(const float4*)(vh + (size_t)(i * 64 + r0) * DIM
                                 + (tc + 1) * KCH + (c4 << 2));
    }
    shortx8 a = *(const shortx8*)(&smA[arow + tc * KCH]);
    #pragma unroll
    for (int dt = 0; dt < 16; ++dt) {
      int brow = half * 256 + dt * 16 + l15;
      shortx8 b = *(const shortx8*)(&smB[cur][brow * LDBS + bu]);
      acc[dt] = __builtin_amdgcn_mfma_f32_16x16x32_bf16(a, b, acc[dt], 0, 0, 0);
    }
    if (tc < 15) {
      __builtin_amdgcn_sched_barrier(0);
      #pragma unroll
      for (int i = 0; i < 8; ++i)
        *(uint2*)(&smB[cur ^ 1][i * 64 * LDBS + sldx]) = cvt4(rv[i]);
      __syncthreads();
      cur ^= 1;
    }
  }

  // ---- Epilogue: store O (fp32) ----
  #pragma unroll
  for (int dt = 0; dt < 16; ++dt) {
    int col = half * 256 + dt * 16 + l15;
    #pragma unroll
    for (int r = 0; r < 4; ++r) {
      oh[(row0 + r) * DIM + col] = acc[dt][r];
    }
  }
}

extern "C" void kernel_launch(void* const* d_in, const int* in_sizes, int n_in,
                              void* d_out, int out_size, void* d_ws, size_t ws_size,
                              hipStream_t stream) {
  const float* q = (const float*)d_in[0];
  const float* k = (const float*)d_in[1];
  const float* v = (const float*)d_in[2];
  float* out = (float*)d_out;
  (void)in_sizes; (void)n_in; (void)out_size; (void)d_ws; (void)ws_size;
  sdpa_kernel<<<dim3(8 * 16 * (SEQ / MQ)), dim3(NTH), 0, stream>>>(q, k, v, out);
}